// Round 1
// baseline (349.669 us; speedup 1.0000x reference)
//
#include <hip/hip_runtime.h>

#define ALPHA_ (-30.0f)
#define EPS_ (1e-4f)
#define LOG2E_ (1.4426950408889634f)

// ---------------------------------------------------------------------------
// Feature kernel: for one (series row n, scale), compute
//   F[n, 64*scale + k] = softmin-pooled sliding MSE between shapelet k and
//   all windows of series row n.
// Layout: lane = shapelet index (64 lanes <-> 64 shapelets), wave = window
// quarter. Series values are wave-uniform (LDS broadcast); shapelet values are
// per-lane register-resident chunks. P=16 windows per lane per step.
// ---------------------------------------------------------------------------

template <int L, int SCALE>
__device__ __forceinline__ void feat_impl(const float* __restrict__ series,
                                          const float* __restrict__ shp,
                                          float* __restrict__ F,
                                          float* smem) {
  constexpr int T = 2048;
  constexpr int W = T - L + 1;
  constexpr int LP = L + 4;              // padded row stride (== 4 mod 8)
  constexpr int P = 16;                  // windows per lane per step
  constexpr int XS_N = 2112;             // series + zero pad
  constexpr int PS_OFF = XS_N;           // prefix sums of squares [0..2048]+pad
  constexpr int PS_N = 2080;
  constexpr int SH_OFF = PS_OFF + PS_N;  // 4192
  constexpr int SH_N = 6400;             // >= 64*LP (max 64*100)
  constexpr int RED_OFF = SH_OFF + SH_N; // 10592, red[512]

  float* xs = smem;
  float* ps = smem + PS_OFF;
  float* sh = smem + SH_OFF;
  float* red = smem + RED_OFF;

  const int n = blockIdx.x;
  const int tid = threadIdx.x;
  const int lane = tid & 63;
  const int wv = tid >> 6;

  // --- stage series row (zero-padded) and shapelets (padded rows) ---
  const float* srow = series + (size_t)n * T;
  for (int i = tid; i < XS_N; i += 256) xs[i] = (i < T) ? srow[i] : 0.f;
  for (int k = wv; k < 64; k += 4)
    for (int l = lane; l < L; l += 64)
      sh[k * LP + l] = shp[k * L + l];
  __syncthreads();

  // --- exclusive prefix sum of x^2 into ps[0..2048] (block scan) ---
  float loc[8];
  float run = 0.f;
#pragma unroll
  for (int i = 0; i < 8; ++i) {
    float v = xs[tid * 8 + i];
    run += v * v;
    loc[i] = run;
  }
  red[tid] = run;
  __syncthreads();
  for (int off = 1; off < 256; off <<= 1) {
    float add = (tid >= off) ? red[tid - off] : 0.f;
    __syncthreads();
    red[tid] += add;
    __syncthreads();
  }
  float excl = red[tid] - run;
#pragma unroll
  for (int i = 0; i < 8; ++i) ps[tid * 8 + 1 + i] = excl + loc[i];
  if (tid == 0) ps[0] = 0.f;
  for (int i = 2049 + tid; i < PS_N; i += 256) ps[i] = 0.f;

  // --- per-lane shapelet squared norm ---
  float s2 = 0.f;
  {
    const float4* r4 = reinterpret_cast<const float4*>(sh + lane * LP);
#pragma unroll
    for (int i = 0; i < L / 4; ++i) {
      float4 v = r4[i];
      s2 += v.x * v.x + v.y * v.y + v.z * v.z + v.w * v.w;
    }
  }
  __syncthreads();  // ps fully written before main loop

  constexpr float INVL = 1.0f / (float)L;
  constexpr float CE = ALPHA_ * LOG2E_ / (float)L;

  // per-wave window range, rounded to multiples of P (keeps w0 16-aligned)
  constexpr int WQ = ((((W + 3) / 4) + P - 1) / P) * P;
  const int wbeg = wv * WQ;
  const int wend = (W < wbeg + WQ) ? W : (wbeg + WQ);

  float esum = 0.f, dsum = 0.f;

  for (int w0 = wbeg; w0 < wend; w0 += P) {
    float acc[P];
#pragma unroll
    for (int p = 0; p < P; ++p) acc[p] = 0.f;

    // rolling x window: xw[i] == xs[w0 + l0 + i]
    float xw[P + 8];
#pragma unroll
    for (int i = 0; i < (P + 8) / 4; ++i) {
      float4 v = *reinterpret_cast<const float4*>(xs + w0 + i * 4);
      xw[i * 4 + 0] = v.x; xw[i * 4 + 1] = v.y;
      xw[i * 4 + 2] = v.z; xw[i * 4 + 3] = v.w;
    }

#pragma unroll
    for (int l0 = 0; l0 < L; l0 += 8) {
      float sv[8];
      {
        float4 v = *reinterpret_cast<const float4*>(sh + lane * LP + l0);
        float4 u = *reinterpret_cast<const float4*>(sh + lane * LP + l0 + 4);
        sv[0] = v.x; sv[1] = v.y; sv[2] = v.z; sv[3] = v.w;
        sv[4] = u.x; sv[5] = u.y; sv[6] = u.z; sv[7] = u.w;
      }
#pragma unroll
      for (int l = 0; l < 8; ++l)
#pragma unroll
        for (int p = 0; p < P; ++p)
          acc[p] = __builtin_fmaf(xw[l + p], sv[l], acc[p]);

      if (l0 + 8 < L) {  // shift rolling window by 8, refill tail
#pragma unroll
        for (int i = 0; i < P; ++i) xw[i] = xw[i + 8];
#pragma unroll
        for (int i = 0; i < 2; ++i) {
          float4 v = *reinterpret_cast<const float4*>(xs + w0 + l0 + P + 8 + i * 4);
          xw[P + i * 4 + 0] = v.x; xw[P + i * 4 + 1] = v.y;
          xw[P + i * 4 + 2] = v.z; xw[P + i * 4 + 3] = v.w;
        }
      }
    }

    // epilogue: d, e = exp(ALPHA*d)+EPS, masked accumulate
    float pl[P], ph[P];
#pragma unroll
    for (int i = 0; i < P / 4; ++i) {
      float4 v = *reinterpret_cast<const float4*>(ps + w0 + i * 4);
      float4 u = *reinterpret_cast<const float4*>(ps + w0 + L + i * 4);
      pl[i * 4 + 0] = v.x; pl[i * 4 + 1] = v.y; pl[i * 4 + 2] = v.z; pl[i * 4 + 3] = v.w;
      ph[i * 4 + 0] = u.x; ph[i * 4 + 1] = u.y; ph[i * 4 + 2] = u.z; ph[i * 4 + 3] = u.w;
    }
#pragma unroll
    for (int p = 0; p < P; ++p) {
      float t = (ph[p] - pl[p]) + s2 - 2.f * acc[p];  // L * d
      float d = t * INVL;
      float e = exp2f(t * CE) + EPS_;
      bool valid = (w0 + p) < wend;
      esum += valid ? e : 0.f;
      dsum += valid ? (d * e) : 0.f;
    }
  }

  // cross-wave reduce (lane k of each wave holds partials for shapelet k)
  red[wv * 64 + lane] = esum;
  red[256 + wv * 64 + lane] = dsum;
  __syncthreads();
  if (tid < 64) {
    float es = red[tid] + red[tid + 64] + red[tid + 128] + red[tid + 192];
    float ds = red[tid + 256] + red[tid + 320] + red[tid + 384] + red[tid + 448];
    F[n * 192 + SCALE * 64 + tid] = ds / es;
  }
}

__global__ void __launch_bounds__(256) feat_kernel(const float* __restrict__ series,
                                                   const float* __restrict__ shp1,
                                                   const float* __restrict__ shp2,
                                                   const float* __restrict__ shp3,
                                                   float* __restrict__ F) {
  __shared__ __align__(16) float smem[11104];
  if (blockIdx.y == 0)
    feat_impl<32, 0>(series, shp1, F, smem);
  else if (blockIdx.y == 1)
    feat_impl<64, 1>(series, shp2, F, smem);
  else
    feat_impl<96, 2>(series, shp3, F, smem);
}

// ---------------------------------------------------------------------------
// Logits + softmax: out[n, :] = softmax(F[n, :] @ W + b)
// ---------------------------------------------------------------------------
__global__ void __launch_bounds__(256) logits_kernel(const float* __restrict__ F,
                                                     const float* __restrict__ Wm,
                                                     const float* __restrict__ bv,
                                                     float* __restrict__ out) {
  __shared__ float Ws[1920];
  __shared__ float bs[16];
  const int tid = threadIdx.x;
  for (int i = tid; i < 1920; i += 256) Ws[i] = Wm[i];
  if (tid < 10) bs[tid] = bv[tid];
  __syncthreads();

  const int n = blockIdx.x * 256 + tid;  // grid.x == 2 -> n in [0, 512)
  float acc[10];
#pragma unroll
  for (int c = 0; c < 10; ++c) acc[c] = bs[c];
  const float* f = F + n * 192;
  for (int j = 0; j < 192; j += 4) {
    float4 v = *reinterpret_cast<const float4*>(f + j);
#pragma unroll
    for (int c = 0; c < 10; ++c)
      acc[c] += v.x * Ws[(j + 0) * 10 + c] + v.y * Ws[(j + 1) * 10 + c] +
                v.z * Ws[(j + 2) * 10 + c] + v.w * Ws[(j + 3) * 10 + c];
  }
  float m = acc[0];
#pragma unroll
  for (int c = 1; c < 10; ++c) m = fmaxf(m, acc[c]);
  float s = 0.f;
  float e[10];
#pragma unroll
  for (int c = 0; c < 10; ++c) {
    e[c] = exp2f((acc[c] - m) * LOG2E_);
    s += e[c];
  }
  float inv = 1.f / s;
#pragma unroll
  for (int c = 0; c < 10; ++c) out[n * 10 + c] = e[c] * inv;
}

extern "C" void kernel_launch(void* const* d_in, const int* in_sizes, int n_in,
                              void* d_out, int out_size, void* d_ws, size_t ws_size,
                              hipStream_t stream) {
  const float* series = (const float*)d_in[0];  // [512, 2048]
  const float* shp1 = (const float*)d_in[1];    // [64, 32]
  const float* shp2 = (const float*)d_in[2];    // [64, 64]
  const float* shp3 = (const float*)d_in[3];    // [64, 96]
  const float* Wm = (const float*)d_in[4];      // [192, 10]
  const float* bv = (const float*)d_in[5];      // [10]
  float* out = (float*)d_out;                   // [512, 10] f32
  float* F = (float*)d_ws;                      // [512, 192] features

  feat_kernel<<<dim3(512, 3), 256, 0, stream>>>(series, shp1, shp2, shp3, F);
  logits_kernel<<<2, 256, 0, stream>>>(F, Wm, bv, out);
}

// Round 2
// 92.287 us; speedup vs baseline: 3.7889x; 3.7889x over previous
//
#include <hip/hip_runtime.h>
#include <hip/hip_bf16.h>

#define ALPHA_ (-30.0f)
#define EPS_ (1e-4f)
#define LOG2E_ (1.4426950408889634f)

typedef short bf16x8 __attribute__((ext_vector_type(8)));
typedef float f32x4 __attribute__((ext_vector_type(4)));

__device__ __forceinline__ short f2bf(float f) {
  __hip_bfloat16 h = __float2bfloat16(f);
  return __builtin_bit_cast(short, h);
}

__device__ __forceinline__ bf16x8 ld_a(const short* p) {
  int2 lo = *reinterpret_cast<const int2*>(p);      // 8B aligned
  int2 hi = *reinterpret_cast<const int2*>(p + 4);
  union { int i[4]; bf16x8 v; } u;
  u.i[0] = lo.x; u.i[1] = lo.y; u.i[2] = hi.x; u.i[3] = hi.y;
  return u.v;
}

__device__ __forceinline__ bf16x8 ld_b(const short* p) {
  union { int4 i; bf16x8 v; } u;
  u.i = *reinterpret_cast<const int4*>(p);          // 16B aligned
  return u.v;
}

// LDS layout (bytes):
//   XC  @ 0     : 4 copies x 2192 bf16 (copy c: Cc[j] = bf16(x[j+c]))  = 17536
//   PS  @ 17536 : prefix sums of x^2, f32[2049]                        =  8208
//   SH  @ 25744 : shapelets bf16 [64][L]   (phase A)                   <= 12288
//   SX  @ 25744 : sumx2 f32[2048]          (phase B, overlays SH)
//   S2  @ 38032 : f32[64]
//   RED @ 38288 : f32[512]
#define XC_OFF 0
#define PS_OFF 17536
#define R2_OFF 25744
#define S2_OFF 38032
#define RED_OFF 38288
#define SMEM_BYTES 40352
#define CL 2192

template <int L, int SCALE>
__device__ __forceinline__ void feat_impl(const float* __restrict__ series,
                                          const float* __restrict__ shp,
                                          float* __restrict__ F,
                                          char* smem) {
  constexpr int T = 2048;
  constexpr int W = T - L + 1;
  constexpr int KT = L / 32;
  constexpr int NIT = (W + 63) / 64;

  short* xc = (short*)(smem + XC_OFF);
  float* ps = (float*)(smem + PS_OFF);
  short* sh = (short*)(smem + R2_OFF);
  float* sx = (float*)(smem + R2_OFF);
  float* s2 = (float*)(smem + S2_OFF);
  float* red = (float*)(smem + RED_OFF);

  const int n = blockIdx.x;
  const int tid = threadIdx.x;
  const int lane = tid & 63;
  const int wv = tid >> 6;
  const int col = lane & 15;
  const int kg = lane >> 4;

  // ---------------- phase 1: stage x (f32 scan + 4 shifted bf16 copies),
  // shapelets (bf16), s2 ----------------
  const float* srow = series + (size_t)n * T;
  float xv[8];
  short bv[8];
  {
    float4 v0 = *reinterpret_cast<const float4*>(srow + tid * 8);
    float4 v1 = *reinterpret_cast<const float4*>(srow + tid * 8 + 4);
    xv[0] = v0.x; xv[1] = v0.y; xv[2] = v0.z; xv[3] = v0.w;
    xv[4] = v1.x; xv[5] = v1.y; xv[6] = v1.z; xv[7] = v1.w;
#pragma unroll
    for (int i = 0; i < 8; ++i) bv[i] = f2bf(xv[i]);
  }
  float loc[8];
  float run = 0.f;
#pragma unroll
  for (int i = 0; i < 8; ++i) { run += xv[i] * xv[i]; loc[i] = run; }
  red[tid] = run;
  __syncthreads();
  for (int off = 1; off < 256; off <<= 1) {
    float add = (tid >= off) ? red[tid - off] : 0.f;
    __syncthreads();
    red[tid] += add;
    __syncthreads();
  }
  float excl = red[tid] - run;
#pragma unroll
  for (int i = 0; i < 8; ++i) ps[tid * 8 + 1 + i] = excl + loc[i];
  if (tid == 0) ps[0] = 0.f;

#pragma unroll
  for (int c = 0; c < 4; ++c) {
    int j0 = tid * 8 - c;
#pragma unroll
    for (int i = 0; i < 8; ++i) {
      int j = j0 + i;
      if (j >= 0) xc[c * CL + j] = bv[i];
    }
  }
#pragma unroll
  for (int c = 0; c < 4; ++c)
    for (int j = 2048 - c + tid; j < CL; j += 256) xc[c * CL + j] = 0;

  for (int i = tid; i < 64 * L; i += 256) sh[i] = f2bf(shp[i]);
  if (tid < 64) {
    float s = 0.f;
    for (int l = 0; l < L; ++l) { float v = shp[tid * L + l]; s += v * v; }
    s2[tid] = s;
  }
  __syncthreads();

  // ---------------- phase 2: B fragments + s2 to registers ----------------
  bf16x8 bfr[KT][4];
#pragma unroll
  for (int kt = 0; kt < KT; ++kt)
#pragma unroll
    for (int nt = 0; nt < 4; ++nt)
      bfr[kt][nt] = ld_b(sh + (nt * 16 + col) * L + kt * 32 + kg * 8);
  float s2c[4];
#pragma unroll
  for (int nt = 0; nt < 4; ++nt) s2c[nt] = s2[nt * 16 + col];
  __syncthreads();

  // ---------------- phase 3: sumx2 (overlays SH) ----------------
  for (int w = tid; w < 2048; w += 256)
    sx[w] = (w < W) ? (ps[w + L] - ps[w]) : 0.f;
  __syncthreads();

  // ---------------- phase 4: main loop (barrier-free) ----------------
  constexpr float CE = ALPHA_ * LOG2E_ / (float)L;
  constexpr float INVL = 1.0f / (float)L;
  const int cc = lane & 3;
  const short* abase = xc + cc * CL + ((lane & 15) - cc + 8 * kg);

  float esum[4] = {0.f, 0.f, 0.f, 0.f};
  float dsum[4] = {0.f, 0.f, 0.f, 0.f};

  for (int it = 0; it < NIT; ++it) {
    const int w0 = it * 64 + wv * 16;
    const short* ap = abase + w0;
    f32x4 acc[4];
#pragma unroll
    for (int nt = 0; nt < 4; ++nt) acc[nt] = (f32x4){0.f, 0.f, 0.f, 0.f};
#pragma unroll
    for (int kt = 0; kt < KT; ++kt) {
      bf16x8 a = ld_a(ap + kt * 32);
#pragma unroll
      for (int nt = 0; nt < 4; ++nt)
        acc[nt] = __builtin_amdgcn_mfma_f32_16x16x32_bf16(a, bfr[kt][nt],
                                                          acc[nt], 0, 0, 0);
    }
    const int wbase = w0 + kg * 4;
    float sxa[4];
    {
      float4 v = *reinterpret_cast<const float4*>(sx + wbase);
      sxa[0] = v.x; sxa[1] = v.y; sxa[2] = v.z; sxa[3] = v.w;
    }
#pragma unroll
    for (int nt = 0; nt < 4; ++nt) {
#pragma unroll
      for (int r = 0; r < 4; ++r) {
        float t = fmaf(-2.f, acc[nt][r], sxa[r] + s2c[nt]);  // L * d
        float e = exp2f(t * CE) + EPS_;
        float em = (wbase + r < W) ? e : 0.f;
        esum[nt] += em;
        dsum[nt] = fmaf(t, em, dsum[nt]);
      }
    }
  }

  // ---------------- phase 5: reduce ----------------
  float fe[4], fd[4];
#pragma unroll
  for (int nt = 0; nt < 4; ++nt) {
    float es = esum[nt], ds = dsum[nt];
    es += __shfl_xor(es, 16, 64);
    es += __shfl_xor(es, 32, 64);
    ds += __shfl_xor(ds, 16, 64);
    ds += __shfl_xor(ds, 32, 64);
    fe[nt] = es; fd[nt] = ds;
  }
  __syncthreads();
  if (lane < 16) {
#pragma unroll
    for (int nt = 0; nt < 4; ++nt) {
      red[wv * 64 + nt * 16 + lane] = fe[nt];
      red[256 + wv * 64 + nt * 16 + lane] = fd[nt];
    }
  }
  __syncthreads();
  if (tid < 64) {
    float es = red[tid] + red[64 + tid] + red[128 + tid] + red[192 + tid];
    float ds = red[256 + tid] + red[320 + tid] + red[384 + tid] + red[448 + tid];
    F[n * 192 + SCALE * 64 + tid] = (ds / es) * INVL;
  }
}

__global__ void __launch_bounds__(256, 4)
feat_kernel(const float* __restrict__ series, const float* __restrict__ shp1,
            const float* __restrict__ shp2, const float* __restrict__ shp3,
            float* __restrict__ F) {
  __shared__ __align__(16) char smem[SMEM_BYTES];
  if (blockIdx.y == 0)
    feat_impl<32, 0>(series, shp1, F, smem);
  else if (blockIdx.y == 1)
    feat_impl<64, 1>(series, shp2, F, smem);
  else
    feat_impl<96, 2>(series, shp3, F, smem);
}

// ---------------------------------------------------------------------------
// Logits + softmax: out[n, :] = softmax(F[n, :] @ W + b)
// ---------------------------------------------------------------------------
__global__ void __launch_bounds__(256) logits_kernel(const float* __restrict__ F,
                                                     const float* __restrict__ Wm,
                                                     const float* __restrict__ bv,
                                                     float* __restrict__ out) {
  __shared__ float Ws[1920];
  __shared__ float bs[16];
  const int tid = threadIdx.x;
  for (int i = tid; i < 1920; i += 256) Ws[i] = Wm[i];
  if (tid < 10) bs[tid] = bv[tid];
  __syncthreads();

  const int n = blockIdx.x * 256 + tid;
  float acc[10];
#pragma unroll
  for (int c = 0; c < 10; ++c) acc[c] = bs[c];
  const float* f = F + n * 192;
  for (int j = 0; j < 192; j += 4) {
    float4 v = *reinterpret_cast<const float4*>(f + j);
#pragma unroll
    for (int c = 0; c < 10; ++c)
      acc[c] += v.x * Ws[(j + 0) * 10 + c] + v.y * Ws[(j + 1) * 10 + c] +
                v.z * Ws[(j + 2) * 10 + c] + v.w * Ws[(j + 3) * 10 + c];
  }
  float m = acc[0];
#pragma unroll
  for (int c = 1; c < 10; ++c) m = fmaxf(m, acc[c]);
  float s = 0.f;
  float e[10];
#pragma unroll
  for (int c = 0; c < 10; ++c) {
    e[c] = exp2f((acc[c] - m) * LOG2E_);
    s += e[c];
  }
  float inv = 1.f / s;
#pragma unroll
  for (int c = 0; c < 10; ++c) out[n * 10 + c] = e[c] * inv;
}

extern "C" void kernel_launch(void* const* d_in, const int* in_sizes, int n_in,
                              void* d_out, int out_size, void* d_ws, size_t ws_size,
                              hipStream_t stream) {
  const float* series = (const float*)d_in[0];  // [512, 2048]
  const float* shp1 = (const float*)d_in[1];    // [64, 32]
  const float* shp2 = (const float*)d_in[2];    // [64, 64]
  const float* shp3 = (const float*)d_in[3];    // [64, 96]
  const float* Wm = (const float*)d_in[4];      // [192, 10]
  const float* bv = (const float*)d_in[5];      // [10]
  float* out = (float*)d_out;                   // [512, 10] f32
  float* F = (float*)d_ws;                      // [512, 192] features

  feat_kernel<<<dim3(512, 3), 256, 0, stream>>>(series, shp1, shp2, shp3, F);
  logits_kernel<<<2, 256, 0, stream>>>(F, Wm, bv, out);
}

// Round 3
// 53.571 us; speedup vs baseline: 6.5272x; 1.7227x over previous
//
#include <hip/hip_runtime.h>
#include <hip/hip_bf16.h>

#define ALPHA_ (-30.0f)
#define EPS_ (1e-4f)
#define LOG2E_ (1.4426950408889634f)

typedef short bf16x8 __attribute__((ext_vector_type(8)));
typedef float f32x4 __attribute__((ext_vector_type(4)));
typedef float f32x2 __attribute__((ext_vector_type(2)));

__device__ __forceinline__ short f2bf(float f) {
  __hip_bfloat16 h = __float2bfloat16(f);
  return __builtin_bit_cast(short, h);
}

__device__ __forceinline__ bf16x8 ld_a(const short* p) {
  int2 lo = *reinterpret_cast<const int2*>(p);      // 8B aligned
  int2 hi = *reinterpret_cast<const int2*>(p + 4);
  union { int i[4]; bf16x8 v; } u;
  u.i[0] = lo.x; u.i[1] = lo.y; u.i[2] = hi.x; u.i[3] = hi.y;
  return u.v;
}

__device__ __forceinline__ bf16x8 ld_b(const short* p) {
  union { int4 i; bf16x8 v; } u;
  u.i = *reinterpret_cast<const int4*>(p);          // 16B aligned
  return u.v;
}

// LDS layout (bytes):
//   XC  @ 0     : 4 copies x 2192 bf16 (copy c: Cc[j] = bf16(x[j+c]))  = 17536
//   PS  @ 17536 : prefix sums of x^2, f32[2049] (+pad)                 =  8208
//   SH  @ 25744 : shapelets bf16 [64][L], scaled by -2*CE; later W     = 12288
//   SX  @ 38032 : CE*sumx2 f32[2048]                                   =  8192
//   S2  @ 46224 : CE*s2 f32[64]                                        =   256
//   RED @ 46480 : f32[512]                                             =  2048
//   FL  @ 48528 : features f32[192]                                    =   768
#define XC_OFF 0
#define PS_OFF 17536
#define SH_OFF 25744
#define SX_OFF 38032
#define S2_OFF 46224
#define RED_OFF 46480
#define FL_OFF 48528
#define SMEM_BYTES 49296
#define CL 2192

template <int L, int SCALE>
__device__ __forceinline__ void scale_pass(const float* __restrict__ shp,
                                           char* smem, int tid, int lane,
                                           int wv, int col, int kg) {
  constexpr int T = 2048;
  constexpr int W = T - L + 1;
  constexpr int KT = L / 32;
  constexpr int NIT = (W + 63) / 64;   // total 64-window iters
  constexpr int M = W / 64;            // fully-valid iters (tail = NIT-M)
  constexpr float CE = ALPHA_ * LOG2E_ / (float)L;  // < 0
  constexpr float SCL = -2.0f * CE;

  short* xc = (short*)(smem + XC_OFF);
  float* ps = (float*)(smem + PS_OFF);
  short* sh = (short*)(smem + SH_OFF);
  float* sx = (float*)(smem + SX_OFF);
  float* s2 = (float*)(smem + S2_OFF);
  float* red = (float*)(smem + RED_OFF);
  float* fl = (float*)(smem + FL_OFF);

  __syncthreads();  // prior users of sh/sx/red done
  // stage shapelets (pre-scaled by -2*CE), sx = CE*sumx2, s2 partials
  for (int i = tid; i < 64 * L; i += 256) sh[i] = f2bf(shp[i] * SCL);
  for (int w = tid; w < 2048; w += 256)
    sx[w] = (w < W) ? CE * (ps[w + L] - ps[w]) : 0.f;
  {
    constexpr int LQ = L / 4;
    const float* sp = shp + (tid & 63) * L + wv * LQ;
    float s = 0.f;
#pragma unroll
    for (int l = 0; l < LQ; ++l) s = fmaf(sp[l], sp[l], s);
    red[tid] = s;
  }
  __syncthreads();
  if (tid < 64)
    s2[tid] = CE * (red[tid] + red[tid + 64] + red[tid + 128] + red[tid + 192]);
  __syncthreads();

  // B fragments + per-lane C-init values
  bf16x8 bfr[KT][4];
#pragma unroll
  for (int kt = 0; kt < KT; ++kt)
#pragma unroll
    for (int nt = 0; nt < 4; ++nt)
      bfr[kt][nt] = ld_b(sh + (nt * 16 + col) * L + kt * 32 + kg * 8);
  float s2c[4];
#pragma unroll
  for (int nt = 0; nt < 4; ++nt) s2c[nt] = s2[nt * 16 + col];

  const int cc = lane & 3;
  const short* ap = xc + cc * CL + (col - cc) + 8 * kg + wv * 16;
  const float* sp2 = sx + wv * 16 + kg * 4;

  f32x2 esP[4], dsP[4];
#pragma unroll
  for (int nt = 0; nt < 4; ++nt) {
    esP[nt] = (f32x2){0.f, 0.f};
    dsP[nt] = (f32x2){0.f, 0.f};
  }

  int it = 0;
  for (; it < M; ++it) {  // fully-valid iterations: no masking
    f32x4 acc[4];
#pragma unroll
    for (int nt = 0; nt < 4; ++nt)
      acc[nt] = (f32x4){s2c[nt], s2c[nt], s2c[nt], s2c[nt]};
#pragma unroll
    for (int kt = 0; kt < KT; ++kt) {
      bf16x8 a = ld_a(ap + kt * 32);
#pragma unroll
      for (int nt = 0; nt < 4; ++nt)
        acc[nt] = __builtin_amdgcn_mfma_f32_16x16x32_bf16(a, bfr[kt][nt],
                                                          acc[nt], 0, 0, 0);
    }
    float4 sv = *reinterpret_cast<const float4*>(sp2);
    f32x2 sx01 = {sv.x, sv.y};
    f32x2 sx23 = {sv.z, sv.w};
#pragma unroll
    for (int nt = 0; nt < 4; ++nt) {
      f32x2 u0 = (f32x2){acc[nt][0], acc[nt][1]} + sx01;  // u = alpha*log2e*d
      f32x2 u1 = (f32x2){acc[nt][2], acc[nt][3]} + sx23;
      f32x2 e0, e1;
      e0.x = __builtin_amdgcn_exp2f(u0.x);
      e0.y = __builtin_amdgcn_exp2f(u0.y);
      e1.x = __builtin_amdgcn_exp2f(u1.x);
      e1.y = __builtin_amdgcn_exp2f(u1.y);
      e0 += (f32x2){EPS_, EPS_};
      e1 += (f32x2){EPS_, EPS_};
      esP[nt] += e0;
      esP[nt] += e1;
      dsP[nt] = __builtin_elementwise_fma(u0, e0, dsP[nt]);
      dsP[nt] = __builtin_elementwise_fma(u1, e1, dsP[nt]);
    }
    ap += 64;
    sp2 += 64;
  }
  for (; it < NIT; ++it) {  // tail: per-element valid mask
    const int wb = it * 64 + wv * 16 + kg * 4;
    f32x4 acc[4];
#pragma unroll
    for (int nt = 0; nt < 4; ++nt)
      acc[nt] = (f32x4){s2c[nt], s2c[nt], s2c[nt], s2c[nt]};
#pragma unroll
    for (int kt = 0; kt < KT; ++kt) {
      bf16x8 a = ld_a(ap + kt * 32);
#pragma unroll
      for (int nt = 0; nt < 4; ++nt)
        acc[nt] = __builtin_amdgcn_mfma_f32_16x16x32_bf16(a, bfr[kt][nt],
                                                          acc[nt], 0, 0, 0);
    }
    float4 sv = *reinterpret_cast<const float4*>(sp2);
    const float svr[4] = {sv.x, sv.y, sv.z, sv.w};
#pragma unroll
    for (int nt = 0; nt < 4; ++nt) {
#pragma unroll
      for (int r = 0; r < 4; ++r) {
        float u = acc[nt][r] + svr[r];
        float e = __builtin_amdgcn_exp2f(u) + EPS_;
        float em = ((wb + r) < W) ? e : 0.f;
        esP[nt].x += em;
        dsP[nt].x = fmaf(u, em, dsP[nt].x);
      }
    }
    ap += 64;
    sp2 += 64;
  }

  // reduce over kg groups (shfl) then over waves (LDS)
  constexpr float ALc = ALPHA_ * LOG2E_;
  float fe[4], fd[4];
#pragma unroll
  for (int nt = 0; nt < 4; ++nt) {
    float es = esP[nt].x + esP[nt].y;
    float ds = dsP[nt].x + dsP[nt].y;
    es += __shfl_xor(es, 16, 64);
    es += __shfl_xor(es, 32, 64);
    ds += __shfl_xor(ds, 16, 64);
    ds += __shfl_xor(ds, 32, 64);
    fe[nt] = es;
    fd[nt] = ds;
  }
  if (lane < 16) {
#pragma unroll
    for (int nt = 0; nt < 4; ++nt) {
      red[wv * 64 + nt * 16 + lane] = fe[nt];
      red[256 + wv * 64 + nt * 16 + lane] = fd[nt];
    }
  }
  __syncthreads();
  if (tid < 64) {
    float es = red[tid] + red[64 + tid] + red[128 + tid] + red[192 + tid];
    float ds = red[256 + tid] + red[320 + tid] + red[384 + tid] + red[448 + tid];
    fl[SCALE * 64 + tid] = ds / (es * ALc);  // = sum(d*e)/sum(e)
  }
}

__global__ void __launch_bounds__(256, 2)
feat_kernel(const float* __restrict__ series, const float* __restrict__ shp1,
            const float* __restrict__ shp2, const float* __restrict__ shp3,
            const float* __restrict__ Wm, const float* __restrict__ bvec,
            float* __restrict__ out) {
  __shared__ __align__(16) char smem[SMEM_BYTES];
  constexpr int T = 2048;

  short* xc = (short*)(smem + XC_OFF);
  float* ps = (float*)(smem + PS_OFF);
  float* red = (float*)(smem + RED_OFF);

  const int n = blockIdx.x;
  const int tid = threadIdx.x;
  const int lane = tid & 63;
  const int wv = tid >> 6;
  const int col = lane & 15;
  const int kg = lane >> 4;

  // ---------- phase A (once): load row, scan x^2, 4 shifted bf16 copies ----
  const float* srow = series + (size_t)n * T;
  float4 v0 = *reinterpret_cast<const float4*>(srow + tid * 8);
  float4 v1 = *reinterpret_cast<const float4*>(srow + tid * 8 + 4);
  float xv[8] = {v0.x, v0.y, v0.z, v0.w, v1.x, v1.y, v1.z, v1.w};
  short bv8[12];
#pragma unroll
  for (int i = 0; i < 8; ++i) bv8[i] = f2bf(xv[i]);
  if (tid < 255) {  // next 4 elements for shifted copies (0 past row end)
    float4 ve = *reinterpret_cast<const float4*>(srow + tid * 8 + 8);
    bv8[8] = f2bf(ve.x); bv8[9] = f2bf(ve.y);
    bv8[10] = f2bf(ve.z); bv8[11] = f2bf(ve.w);
  } else {
    bv8[8] = bv8[9] = bv8[10] = bv8[11] = 0;
  }

  float loc[8];
  float run = 0.f;
#pragma unroll
  for (int i = 0; i < 8; ++i) {
    run = fmaf(xv[i], xv[i], run);
    loc[i] = run;
  }
  // wave-level inclusive scan of per-thread sums
  float sc = run;
#pragma unroll
  for (int off = 1; off < 64; off <<= 1) {
    float t = __shfl_up(sc, off, 64);
    if (lane >= off) sc += t;
  }
  if (lane == 63) red[wv] = sc;
  __syncthreads();
  float wb0 = 0.f;
  for (int w = 0; w < wv; ++w) wb0 += red[w];
  float excl = wb0 + sc - run;
#pragma unroll
  for (int i = 0; i < 8; ++i) ps[tid * 8 + 1 + i] = excl + loc[i];
  if (tid == 0) ps[0] = 0.f;

#pragma unroll
  for (int c = 0; c < 4; ++c) {  // one ds_write_b128 per copy
    union { short s[8]; int4 q; } u;
#pragma unroll
    for (int i = 0; i < 8; ++i) u.s[i] = bv8[i + c];
    *reinterpret_cast<int4*>(xc + c * CL + tid * 8) = u.q;
  }
  if (tid < CL - 2048) {
    int j = 2048 + tid;
#pragma unroll
    for (int c = 0; c < 4; ++c) xc[c * CL + j] = 0;
  }
  // (scale_pass starts with __syncthreads())

  scale_pass<32, 0>(shp1, smem, tid, lane, wv, col, kg);
  scale_pass<64, 1>(shp2, smem, tid, lane, wv, col, kg);
  scale_pass<96, 2>(shp3, smem, tid, lane, wv, col, kg);

  // ---------- fused logits + softmax ----------
  __syncthreads();  // FL complete; SH region free
  float* wl = (float*)(smem + SH_OFF);
  const float* flp = (const float*)(smem + FL_OFF);
  for (int i = tid; i < 1920; i += 256) wl[i] = Wm[i];
  __syncthreads();
  float acc = 0.f;
  if (tid < 10) {
    acc = bvec[tid];
#pragma unroll 8
    for (int j = 0; j < 192; ++j) acc = fmaf(flp[j], wl[j * 10 + tid], acc);
    red[tid] = acc;
  }
  __syncthreads();
  if (tid < 10) {
    float m = red[0];
#pragma unroll
    for (int j = 1; j < 10; ++j) m = fmaxf(m, red[j]);
    float s = 0.f;
#pragma unroll
    for (int j = 0; j < 10; ++j)
      s += __builtin_amdgcn_exp2f((red[j] - m) * LOG2E_);
    out[(size_t)n * 10 + tid] = __builtin_amdgcn_exp2f((acc - m) * LOG2E_) / s;
  }
}

extern "C" void kernel_launch(void* const* d_in, const int* in_sizes, int n_in,
                              void* d_out, int out_size, void* d_ws, size_t ws_size,
                              hipStream_t stream) {
  const float* series = (const float*)d_in[0];  // [512, 2048]
  const float* shp1 = (const float*)d_in[1];    // [64, 32]
  const float* shp2 = (const float*)d_in[2];    // [64, 64]
  const float* shp3 = (const float*)d_in[3];    // [64, 96]
  const float* Wm = (const float*)d_in[4];      // [192, 10]
  const float* bv = (const float*)d_in[5];      // [10]
  float* out = (float*)d_out;                   // [512, 10] f32

  feat_kernel<<<512, 256, 0, stream>>>(series, shp1, shp2, shp3, Wm, bv, out);
}